// Round 1
// baseline (581.810 us; speedup 1.0000x reference)
//
#include <hip/hip_runtime.h>

// Problem constants: B=4, L=256, E=2 (both ensembles), D=512, H=8, dk=dv=64, KG=16.
// All fp32. Workspace layout (floats, 1M = 1048576):
//   qp:0  qp2:1M  kp:2M  kp2:3M  vp:4M  pre:5M  fcb:6M  scores:7M..15M
// Total ws requirement: 15*1048576*4 = 62.9 MB.

static __device__ __forceinline__ float4 ld4(const float* p) {
    return *reinterpret_cast<const float4*>(p);
}

// ---------------------------------------------------------------------------
// K1/K6: generic tiled GEMM, 64x64 tile, BK=16, 256 threads, 4x4 per thread.
// M=1024 rows (b*256+l), K=512, N=512. A row pointer = A + m*1024 + ens*512.
// mode 0: qp/kp-style output [ (b*2+ens)*8+h ][ l ][ d ]   (h=n>>6, d=n&63)
// mode 1: vp output          [ b*8+h ][ l*2+ens ][ d ]
// mode 2: fc output          [ (m*2+ens) ][ n ]
// ---------------------------------------------------------------------------
__global__ __launch_bounds__(256) void gemm_k(
    const float* __restrict__ qin, const float* __restrict__ kin, const float* __restrict__ vin,
    const float* __restrict__ Wq, const float* __restrict__ Wk, const float* __restrict__ Wv,
    const float* __restrict__ Wq2, const float* __restrict__ Wk2,
    const float* __restrict__ prebuf, const float* __restrict__ Wfc,
    float* __restrict__ qp, float* __restrict__ qp2, float* __restrict__ kp,
    float* __restrict__ kp2, float* __restrict__ vp, float* __restrict__ fcb,
    int mm_base)
{
    __shared__ float As[64][17];   // pad 17: conflict-free column reads
    __shared__ float Bs[16][64];   // float4-aligned rows

    const int mm = mm_base + (int)blockIdx.z;
    const float* A; const float* W; float* Cb; int ens; int mode;
    switch (mm) {
        case 0:  A=qin;    W=Wq;           Cb=qp;  ens=0; mode=0; break;
        case 1:  A=qin;    W=Wq + 262144;  Cb=qp;  ens=1; mode=0; break;
        case 2:  A=qin;    W=Wq2;          Cb=qp2; ens=0; mode=0; break;
        case 3:  A=qin;    W=Wq2 + 262144; Cb=qp2; ens=1; mode=0; break;
        case 4:  A=kin;    W=Wk;           Cb=kp;  ens=0; mode=0; break;
        case 5:  A=kin;    W=Wk + 262144;  Cb=kp;  ens=1; mode=0; break;
        case 6:  A=kin;    W=Wk2;          Cb=kp2; ens=0; mode=0; break;
        case 7:  A=kin;    W=Wk2 + 262144; Cb=kp2; ens=1; mode=0; break;
        case 8:  A=vin;    W=Wv;           Cb=vp;  ens=0; mode=1; break;
        case 9:  A=vin;    W=Wv + 262144;  Cb=vp;  ens=1; mode=1; break;
        case 10: A=prebuf; W=Wfc;          Cb=fcb; ens=0; mode=2; break;
        default: A=prebuf; W=Wfc + 262144; Cb=fcb; ens=1; mode=2; break;
    }

    const int tid = threadIdx.x;
    const int m0 = blockIdx.y * 64;
    const int n0 = blockIdx.x * 64;
    const int ty = tid >> 4, tx = tid & 15;
    const int ar = tid >> 2, ac = (tid & 3) * 4;   // A tile: 64 rows x 16 k
    const int br = tid >> 4, bc = (tid & 15) * 4;  // B tile: 16 k x 64 n

    float acc[4][4] = {};

    for (int kt = 0; kt < 512; kt += 16) {
        float4 av = ld4(A + (size_t)(m0 + ar) * 1024 + ens * 512 + kt + ac);
        float4 bv = ld4(W + (size_t)(kt + br) * 512 + n0 + bc);
        __syncthreads();
        As[ar][ac + 0] = av.x; As[ar][ac + 1] = av.y;
        As[ar][ac + 2] = av.z; As[ar][ac + 3] = av.w;
        *reinterpret_cast<float4*>(&Bs[br][bc]) = bv;
        __syncthreads();
        #pragma unroll
        for (int kk = 0; kk < 16; ++kk) {
            float a0 = As[ty*4+0][kk];
            float a1 = As[ty*4+1][kk];
            float a2 = As[ty*4+2][kk];
            float a3 = As[ty*4+3][kk];
            float4 b4 = *reinterpret_cast<const float4*>(&Bs[kk][tx*4]);
            acc[0][0] += a0*b4.x; acc[0][1] += a0*b4.y; acc[0][2] += a0*b4.z; acc[0][3] += a0*b4.w;
            acc[1][0] += a1*b4.x; acc[1][1] += a1*b4.y; acc[1][2] += a1*b4.z; acc[1][3] += a1*b4.w;
            acc[2][0] += a2*b4.x; acc[2][1] += a2*b4.y; acc[2][2] += a2*b4.z; acc[2][3] += a2*b4.w;
            acc[3][0] += a3*b4.x; acc[3][1] += a3*b4.y; acc[3][2] += a3*b4.z; acc[3][3] += a3*b4.w;
        }
    }

    #pragma unroll
    for (int u = 0; u < 4; ++u) {
        const int m = m0 + ty * 4 + u;
        const int b = m >> 8, l = m & 255;
        #pragma unroll
        for (int w = 0; w < 4; ++w) {
            const int n = n0 + tx * 4 + w;
            const int h = n >> 6, d = n & 63;
            size_t dst;
            if (mode == 0)      dst = ((size_t)((b*2 + ens)*8 + h) * 256 + l) * 64 + d;
            else if (mode == 1) dst = ((size_t)(b*8 + h) * 512 + l*2 + ens) * 64 + d;
            else                dst = ((size_t)m*2 + ens) * 512 + n;
            Cb[dst] = acc[u][w];
        }
    }
}

// ---------------------------------------------------------------------------
// K2: gate MLP. One block = 64 consecutive (b,q,l) rows (same b,q) x 32 combos.
// Thread (bl,c): bl=tid>>5 (8 row-groups), c=tid&31 (combo (i*2+j)*8+h).
// Writes log_sigmoid(agg) directly into scores[bih][q][k*2+j] (K3 does RMW add).
// ---------------------------------------------------------------------------
__global__ __launch_bounds__(256) void mlp_k(
    const float* __restrict__ gr_mask, const int* __restrict__ mask,
    const float* __restrict__ grW1, const float* __restrict__ grb1,
    const float* __restrict__ grW2, const float* __restrict__ grb2,
    float* __restrict__ scores)
{
    __shared__ float w1s[256][33];  // [(g*16+m)][c], pad 33 -> conflict-free over c
    __shared__ float b1s[16][33];   // [m][c]
    __shared__ float w2s[16][33];   // [m][c]
    __shared__ float b2s[32];
    __shared__ float ts[64][17];    // [row_local][g]
    __shared__ float ls[64][33];    // [row_local][c] staging for coalesced writeout

    const int tid = threadIdx.x;
    const int row_base = blockIdx.x * 64;
    const int b  = row_base >> 16;
    const int q  = (row_base >> 8) & 255;
    const int l0 = row_base & 255;

    #pragma unroll
    for (int it = 0; it < 32; ++it) {               // grW1: 8192 = c*256 + g*16 + m
        int flat = tid + it * 256;
        w1s[flat & 255][flat >> 8] = grW1[flat];
    }
    #pragma unroll
    for (int it = 0; it < 2; ++it) {                // grb1 / grW2: 512 = c*16 + m
        int flat = tid + it * 256;
        b1s[flat & 15][flat >> 4] = grb1[flat];
        w2s[flat & 15][flat >> 4] = grW2[flat];
    }
    if (tid < 32) b2s[tid] = grb2[tid];
    #pragma unroll
    for (int it = 0; it < 4; ++it) {                // t[b,q,l,g] = gr_mask[b,g,q,l]
        int flat = tid + it * 256;                  // 64 rows x 16 g
        int g = flat >> 6, r = flat & 63;
        ts[r][g] = gr_mask[(size_t)(b*16 + g) * 65536 + q * 256 + l0 + r];
    }
    __syncthreads();

    const int bl = tid >> 5, c = tid & 31;
    for (int r = 0; r < 8; ++r) {
        const int rl = r * 8 + bl;
        float tval[16];
        #pragma unroll
        for (int g = 0; g < 16; ++g) tval[g] = ts[rl][g];
        float agg = b2s[c];
        #pragma unroll
        for (int m = 0; m < 16; ++m) {
            float a = b1s[m][c];
            #pragma unroll
            for (int g = 0; g < 16; ++g) a += tval[g] * w1s[g*16 + m][c];
            agg += fmaxf(a, 0.f) * w2s[m][c];
        }
        if (mask[(size_t)(b*256 + q) * 256 + l0 + rl] == 0) agg = 0.f;
        // stable log-sigmoid
        ls[rl][c] = fminf(agg, 0.f) - log1pf(expf(-fabsf(agg)));
    }
    __syncthreads();

    // writeout: scores[(((b*2+i)*8+h)*256+q)*512 + k*2 + j], k = l0+r2, c2=(i*2+j)*8+h
    #pragma unroll
    for (int it = 0; it < 8; ++it) {
        int flat = tid + it * 256;      // 32 c x 64 r
        int c2 = flat >> 6, r2 = flat & 63;
        int ii = c2 >> 4, jj = (c2 >> 3) & 1, hh = c2 & 7;
        size_t dst = ((size_t)((b*2 + ii)*8 + hh) * 256 + q) * 512 + (size_t)(l0 + r2) * 2 + jj;
        scores[dst] = ls[r2][c2];
    }
}

// ---------------------------------------------------------------------------
// K3: scores. Block: fixed (b,i,h,j), 32x32 (q,k) tile. s1/s2 dots over d=64,
// gate with tril(adj), add the staged log-sigmoid (RMW), apply mask.
// ---------------------------------------------------------------------------
__global__ __launch_bounds__(256) void scores_k(
    const float* __restrict__ qp, const float* __restrict__ qp2,
    const float* __restrict__ kp, const float* __restrict__ kp2,
    const float* __restrict__ adj, const int* __restrict__ mask,
    float* __restrict__ scores)
{
    __shared__ float q1s[32][65], q2s[32][65], k1s[32][65], k2s[32][65];

    const int z = blockIdx.z;
    const int bih = z >> 1, j = z & 1;
    const int b = bih >> 4, i = (bih >> 3) & 1, h = bih & 7;
    const int bjh = (b*2 + j)*8 + h;
    const int q0 = blockIdx.y * 32, k0 = blockIdx.x * 32;
    const int tid = threadIdx.x;

    const float* q1g = qp  + (size_t)bih * 16384 + q0 * 64;
    const float* q2g = qp2 + (size_t)bih * 16384 + q0 * 64;
    const float* k1g = kp  + (size_t)bjh * 16384 + k0 * 64;
    const float* k2g = kp2 + (size_t)bjh * 16384 + k0 * 64;
    #pragma unroll
    for (int it = 0; it < 2; ++it) {
        int idx4 = tid * 2 + it;            // 512 float4 per tile
        int r = idx4 >> 4, c4 = (idx4 & 15) * 4;
        float4 a = ld4(q1g + r*64 + c4);
        float4 e = ld4(q2g + r*64 + c4);
        float4 f = ld4(k1g + r*64 + c4);
        float4 g = ld4(k2g + r*64 + c4);
        q1s[r][c4+0]=a.x; q1s[r][c4+1]=a.y; q1s[r][c4+2]=a.z; q1s[r][c4+3]=a.w;
        q2s[r][c4+0]=e.x; q2s[r][c4+1]=e.y; q2s[r][c4+2]=e.z; q2s[r][c4+3]=e.w;
        k1s[r][c4+0]=f.x; k1s[r][c4+1]=f.y; k1s[r][c4+2]=f.z; k1s[r][c4+3]=f.w;
        k2s[r][c4+0]=g.x; k2s[r][c4+1]=g.y; k2s[r][c4+2]=g.z; k2s[r][c4+3]=g.w;
    }
    __syncthreads();

    const int tk = tid & 31, tq = tid >> 5;   // tq 0..7, 4 q-rows per thread
    float acc1[4] = {}, acc2[4] = {};
    for (int dd = 0; dd < 64; ++dd) {
        float kv1 = k1s[tk][dd], kv2 = k2s[tk][dd];
        #pragma unroll
        for (int u = 0; u < 4; ++u) {
            acc1[u] += q1s[tq*4 + u][dd] * kv1;
            acc2[u] += q2s[tq*4 + u][dd] * kv2;
        }
    }

    const int kg = k0 + tk;
    #pragma unroll
    for (int u = 0; u < 4; ++u) {
        const int qg = q0 + tq*4 + u;
        const size_t mi = (size_t)(b*256 + qg) * 256 + kg;
        float gate = (qg >= kg) ? adj[mi] : 0.f;   // tril includes diagonal
        float s = (acc1[u] * gate + acc2[u] * (1.f - gate)) * 0.125f; // /sqrt(64)
        const size_t sidx = ((size_t)bih * 256 + qg) * 512 + (size_t)kg * 2 + j;
        s += scores[sidx];                          // staged log-sigmoid term
        if (mask[mi] == 0) s = -1e9f;
        scores[sidx] = s;
    }
}

// ---------------------------------------------------------------------------
// K4: softmax over 512 (k,j) per row. 4 waves/block, one row per wave.
// ---------------------------------------------------------------------------
__global__ __launch_bounds__(256) void softmax_k(float* __restrict__ scores)
{
    const int row  = blockIdx.x * 4 + (threadIdx.x >> 6);
    const int lane = threadIdx.x & 63;
    float* p = scores + (size_t)row * 512 + lane * 8;
    float4 v0 = *reinterpret_cast<float4*>(p);
    float4 v1 = *reinterpret_cast<float4*>(p + 4);
    float v[8] = {v0.x, v0.y, v0.z, v0.w, v1.x, v1.y, v1.z, v1.w};

    float m = v[0];
    #pragma unroll
    for (int t = 1; t < 8; ++t) m = fmaxf(m, v[t]);
    #pragma unroll
    for (int off = 32; off > 0; off >>= 1) m = fmaxf(m, __shfl_xor(m, off));

    float s = 0.f;
    #pragma unroll
    for (int t = 0; t < 8; ++t) { v[t] = expf(v[t] - m); s += v[t]; }
    #pragma unroll
    for (int off = 32; off > 0; off >>= 1) s += __shfl_xor(s, off);

    const float inv = 1.f / s;
    v0 = make_float4(v[0]*inv, v[1]*inv, v[2]*inv, v[3]*inv);
    v1 = make_float4(v[4]*inv, v[5]*inv, v[6]*inv, v[7]*inv);
    *reinterpret_cast<float4*>(p)     = v0;
    *reinterpret_cast<float4*>(p + 4) = v1;
}

// ---------------------------------------------------------------------------
// K5: PV. Block: fixed (b,i,h), 32 q-rows. attn[256x512] @ vp[512x64].
// ---------------------------------------------------------------------------
__global__ __launch_bounds__(256) void pv_k(
    const float* __restrict__ attn, const float* __restrict__ vp,
    float* __restrict__ pre)
{
    __shared__ float as_[32][65];
    __shared__ float vs[64][65];

    const int bih = blockIdx.y;
    const int b = bih >> 4, i = (bih >> 3) & 1, h = bih & 7;
    const int q0 = blockIdx.x * 32;
    const int tid = threadIdx.x;
    const int d = tid & 63, qb = tid >> 6;   // qb 0..3, 8 q-rows per thread

    const float* ag = attn + ((size_t)bih * 256 + q0) * 512;
    const float* vg = vp + (size_t)(b*8 + h) * 32768;

    float acc[8] = {};
    for (int kc = 0; kc < 512; kc += 64) {
        __syncthreads();
        #pragma unroll
        for (int it = 0; it < 2; ++it) {         // attn 32x64
            int idx4 = tid * 2 + it;
            int r = idx4 >> 4, c4 = (idx4 & 15) * 4;
            float4 a = ld4(ag + (size_t)r * 512 + kc + c4);
            as_[r][c4+0]=a.x; as_[r][c4+1]=a.y; as_[r][c4+2]=a.z; as_[r][c4+3]=a.w;
        }
        #pragma unroll
        for (int it = 0; it < 4; ++it) {         // vp 64x64
            int idx4 = tid + it * 256;
            int r = idx4 >> 4, c4 = (idx4 & 15) * 4;
            float4 a = ld4(vg + (size_t)(kc + r) * 64 + c4);
            vs[r][c4+0]=a.x; vs[r][c4+1]=a.y; vs[r][c4+2]=a.z; vs[r][c4+3]=a.w;
        }
        __syncthreads();
        for (int kk = 0; kk < 64; ++kk) {
            float vv = vs[kk][d];
            #pragma unroll
            for (int u = 0; u < 8; ++u) acc[u] += as_[qb*8 + u][kk] * vv;
        }
    }
    #pragma unroll
    for (int u = 0; u < 8; ++u) {
        const int qg = q0 + qb*8 + u;
        pre[((size_t)(b*256 + qg) * 2 + i) * 512 + h*64 + d] = acc[u];
    }
}

// ---------------------------------------------------------------------------
// K7: residual + LayerNorm over D=512. One block per (b,q,i) row.
// ---------------------------------------------------------------------------
__global__ __launch_bounds__(256) void ln_k(
    const float* __restrict__ fcb, const float* __restrict__ qin,
    const float* __restrict__ lng, const float* __restrict__ lnb,
    float* __restrict__ out)
{
    __shared__ float red[8];
    const int row = blockIdx.x;
    const int tid = threadIdx.x;
    const float* fr = fcb + (size_t)row * 512;
    const float* qr = qin + (size_t)row * 512;
    float v0 = fr[tid]       + qr[tid];
    float v1 = fr[tid + 256] + qr[tid + 256];
    float s  = v0 + v1;
    float sq = v0*v0 + v1*v1;
    #pragma unroll
    for (int off = 32; off > 0; off >>= 1) {
        s  += __shfl_xor(s, off);
        sq += __shfl_xor(sq, off);
    }
    const int w = tid >> 6;
    if ((tid & 63) == 0) { red[w*2] = s; red[w*2 + 1] = sq; }
    __syncthreads();
    s  = red[0] + red[2] + red[4] + red[6];
    sq = red[1] + red[3] + red[5] + red[7];
    const float mu  = s * (1.f / 512.f);
    const float var = sq * (1.f / 512.f) - mu * mu;
    const float rs  = rsqrtf(var + 1e-6f);
    out[(size_t)row * 512 + tid]       = (v0 - mu) * rs * lng[tid]       + lnb[tid];
    out[(size_t)row * 512 + tid + 256] = (v1 - mu) * rs * lng[tid + 256] + lnb[tid + 256];
}

// ---------------------------------------------------------------------------
extern "C" void kernel_launch(void* const* d_in, const int* in_sizes, int n_in,
                              void* d_out, int out_size, void* d_ws, size_t ws_size,
                              hipStream_t stream) {
    (void)in_sizes; (void)n_in; (void)out_size; (void)ws_size;
    const float* qin    = (const float*)d_in[0];
    const float* kin    = (const float*)d_in[1];
    const float* vin    = (const float*)d_in[2];
    const int*   maskp  = (const int*)  d_in[3];
    const float* grm    = (const float*)d_in[4];
    const float* adj    = (const float*)d_in[5];
    const float* Wq     = (const float*)d_in[6];
    const float* Wk     = (const float*)d_in[7];
    const float* Wv     = (const float*)d_in[8];
    const float* Wq2    = (const float*)d_in[9];
    const float* Wk2    = (const float*)d_in[10];
    // d_in[11] = Wv2 (unused by the reference math)
    const float* Wfc    = (const float*)d_in[12];
    const float* grW1   = (const float*)d_in[13];
    const float* grb1   = (const float*)d_in[14];
    const float* grW2   = (const float*)d_in[15];
    const float* grb2   = (const float*)d_in[16];
    const float* lng    = (const float*)d_in[17];
    const float* lnb    = (const float*)d_in[18];
    float* out = (float*)d_out;

    float* ws = (float*)d_ws;
    const size_t M1 = 1048576;
    float* qp     = ws;
    float* qp2    = ws + 1*M1;
    float* kp     = ws + 2*M1;
    float* kp2    = ws + 3*M1;
    float* vp     = ws + 4*M1;
    float* pre    = ws + 5*M1;
    float* fcb    = ws + 6*M1;
    float* scores = ws + 7*M1;   // 8M floats

    // 1) projections: qp, qp2, kp, kp2, vp
    gemm_k<<<dim3(8, 16, 10), 256, 0, stream>>>(qin, kin, vin, Wq, Wk, Wv, Wq2, Wk2,
                                                pre, Wfc, qp, qp2, kp, kp2, vp, fcb, 0);
    // 2) gate MLP -> log_sigmoid staged into scores
    mlp_k<<<4096, 256, 0, stream>>>(grm, maskp, grW1, grb1, grW2, grb2, scores);
    // 3) scores (QK^T gate + staged lsig + mask)
    scores_k<<<dim3(8, 8, 128), 256, 0, stream>>>(qp, qp2, kp, kp2, adj, maskp, scores);
    // 4) softmax over (k,j)
    softmax_k<<<4096, 256, 0, stream>>>(scores);
    // 5) attn @ V -> pre
    pv_k<<<dim3(8, 64), 256, 0, stream>>>(scores, vp, pre);
    // 6) FC
    gemm_k<<<dim3(8, 16, 2), 256, 0, stream>>>(qin, kin, vin, Wq, Wk, Wv, Wq2, Wk2,
                                               pre, Wfc, qp, qp2, kp, kp2, vp, fcb, 10);
    // 7) residual + LayerNorm
    ln_k<<<2048, 256, 0, stream>>>(fcb, qin, lng, lnb, out);
}